// Round 16
// baseline (2527.684 us; speedup 1.0000x reference)
//
#include <hip/hip_runtime.h>
#include <stdint.h>

typedef _Float16 f16;
typedef _Float16 f16x8 __attribute__((ext_vector_type(8)));
typedef float    f32x4 __attribute__((ext_vector_type(4)));

#define Bm 64
#define Ss 512
#define Ff 512
#define Hh 1024
#define Oo 512
#define NWG 256          // {L0,L1} x {half0,half1} x 64 col-groups
#define HBh (Bm*Hh)
#define SLOTB (HBh*2)    // 131072 B per slot

// ---- flag layout: flags[layer][half][cg], 64B stride ----
#define FL0_U32 0                        // flags0[half*64+cg] at u32 16*idx
#define FL1_U32 4096                     // flags1[...] at byte 16384
// ---- write-once layout: slot k holds h(k-1); slot 0 = zeros ----
#define NSLOT 513
#define H0F_BYTE ((size_t)65536)
#define H1F_BYTE (H0F_BYTE + (size_t)NSLOT*SLOTB)
#define WSF_NEED (H1F_BYTE + (size_t)NSLOT*SLOTB)   // ~134.5 MB

#define MFMA16 __builtin_amdgcn_mfma_f32_16x16x32_f16

__device__ __forceinline__ float sigm(float x){ return 1.0f/(1.0f+__expf(-x)); }
__device__ __forceinline__ float tanhf_(float x){
  x = fminf(15.0f, fmaxf(-15.0f, x));
  float e = __expf(-2.0f*x);
  return (1.0f - e)/(1.0f + e);
}

__global__ void init_fresh(void* ws){
  const uint4 z = {0,0,0,0};
  int idx = blockIdx.x*blockDim.x + threadIdx.x;
  const int total = 4096 + 8192 + 8192;   // 64KB flags + h0 slot0 + h1 slot0
  for (int i = idx; i < total; i += gridDim.x*blockDim.x) {
    if (i < 4096)        ((uint4*)ws)[i] = z;
    else if (i < 12288)  ((uint4*)((char*)ws + H0F_BYTE))[i-4096]  = z;
    else                 ((uint4*)((char*)ws + H1F_BYTE))[i-12288] = z;
  }
}

// ---- sync primitives ----
__device__ __forceinline__ void setflag(unsigned* p, unsigned v){
  asm volatile("global_atomic_swap %0, %1, off" :: "v"(p), "v"(v) : "memory");
}

// wave-local poll: THIS wave's 64 lanes poll one flag set; no WG barrier.
// Each wave waits only on its own dependency (kh=0 -> fl0, kh=1 -> fl1),
// so h0-side work overlaps the h1 wait on L1's critical cycle.
__device__ __forceinline__ void pollwave(unsigned* wsu, int fb, unsigned tgt){
  const unsigned* p = wsu + fb + 16*(threadIdx.x & 63);
  for (;;) {
    unsigned v;
    asm volatile("global_load_dword %0, %1, off sc0 sc1\n\t"
                 "s_waitcnt vmcnt(0)"
                 : "=&v"(v) : "v"(p) : "memory");
    if (__all(v >= tgt)) break;
    __builtin_amdgcn_s_sleep(1);
  }
  __builtin_amdgcn_sched_barrier(0);   // rule #18: pin consumers below
}

// WG-level poll (projection only)
__device__ __forceinline__ void poll2(unsigned* wsu, int fb0, unsigned tgt0,
                                      int fb1, unsigned tgt1, int tid){
  if (tid < 64) {
    const unsigned* p0 = wsu + fb0 + 16*tid;
    const unsigned* p1 = wsu + fb1 + 16*tid;
    for (;;) {
      unsigned v0, v1;
      asm volatile("global_load_dword %0, %2, off sc0 sc1\n\t"
                   "global_load_dword %1, %3, off sc0 sc1\n\t"
                   "s_waitcnt vmcnt(0)"
                   : "=&v"(v0), "=&v"(v1) : "v"(p0), "v"(p1) : "memory");
      if (__all((v0 >= tgt0) && (v1 >= tgt1))) break;
      __builtin_amdgcn_s_sleep(1);
    }
  }
  asm volatile("s_waitcnt vmcnt(0)" ::: "memory");
  __builtin_amdgcn_sched_barrier(0);
  __syncthreads();
}

// write-once-slot batch: 8 PLAIN CACHED 16B loads (L2 multicast across the
// same-(layer,half) WGs per XCD); pointers pre-offset +4096; each pointer
// serves a ks pair via offsets {-4096, 0}.
#define ISSUE8T(A, P0, P1, P2, P3) asm volatile( \
  "global_load_dwordx4 %0, %8, off offset:-4096\n\t" \
  "global_load_dwordx4 %1, %8, off\n\t" \
  "global_load_dwordx4 %2, %9, off offset:-4096\n\t" \
  "global_load_dwordx4 %3, %9, off\n\t" \
  "global_load_dwordx4 %4, %10, off offset:-4096\n\t" \
  "global_load_dwordx4 %5, %10, off\n\t" \
  "global_load_dwordx4 %6, %11, off offset:-4096\n\t" \
  "global_load_dwordx4 %7, %11, off" \
  : "=&v"(A[0]), "=&v"(A[1]), "=&v"(A[2]), "=&v"(A[3]), \
    "=&v"(A[4]), "=&v"(A[5]), "=&v"(A[6]), "=&v"(A[7]) \
  : "v"(P0), "v"(P1), "v"(P2), "v"(P3) : "memory")

#define WAITV(N) do{ asm volatile("s_waitcnt vmcnt(" #N ")" ::: "memory"); \
                     __builtin_amdgcn_sched_barrier(0x106); }while(0)

// 8 k-steps of DUAL-gate MFMA; F weights at ks, C weights at KSC+ks
#define CONS8D(Aarr, KSB, KSC) do{ \
  _Pragma("unroll") \
  for (int j = 0; j < 8; ++j){ \
    f16x8 bw = ldsA[(size_t)((KSB)+j)*64]; \
    f16x8 cw = ldsA[(size_t)((KSC)+(KSB)+j)*64]; \
    if (j & 1){ aF1 = MFMA16(Aarr[j], bw, aF1, 0,0,0); aC1 = MFMA16(Aarr[j], cw, aC1, 0,0,0); } \
    else      { aF0 = MFMA16(Aarr[j], bw, aF0, 0,0,0); aC0 = MFMA16(Aarr[j], cw, aC0, 0,0,0); } \
  } \
}while(0)

__device__ __forceinline__ f16x8 cvt8(float4 v0, float4 v1){
  f16x8 a;
  a[0]=v0.x; a[1]=v0.y; a[2]=v0.z; a[3]=v0.w;
  a[4]=v1.x; a[5]=v1.y; a[6]=v1.z; a[7]=v1.w;
  return a;
}

__global__ __launch_bounds__(256,1) void janet_persistent(
    const float* __restrict__ x,
    const float* __restrict__ Wf0, const float* __restrict__ bf0,
    const float* __restrict__ Wc0, const float* __restrict__ bc0,
    const float* __restrict__ Wf1, const float* __restrict__ bf1,
    const float* __restrict__ Wc1, const float* __restrict__ bc1,
    const float* __restrict__ Wfc, const float* __restrict__ bfc,
    float* __restrict__ out, void* __restrict__ ws)
{
  __shared__ __align__(16) unsigned char smem[135168];   // 128KB W + 4KB xchg
  __builtin_amdgcn_fence(__ATOMIC_ACQUIRE, "agent");     // write-once scheme

  unsigned* wsu = (unsigned*)ws;
  char* h0base = (char*)ws + H0F_BYTE;
  char* h1base = (char*)ws + H1F_BYTE;

  const int wid  = blockIdx.x;
  const int tid  = threadIdx.x;
  const bool isL0 = (wid < 128);
  const int half = (wid >> 6) & 1;
  const int lw   = wid & 63;           // col-group
  const int col0 = lw * 16;
  const int K    = isL0 ? (Ff + Hh) : (2*Hh);   // 1536 / 2048
  const int KS   = K >> 5;                      // 48 / 64

  // ---- stage weights into LDS in MFMA B-fragment order [gate][ks][lane] ----
  {
    const float* Wg[2] = { isL0 ? Wf0 : Wf1, isL0 ? Wc0 : Wc1 };
    for (int g = 0; g < 2; ++g) {
      const float* W = Wg[g];
      for (int e = tid; e < 16*K; e += 256) {
        int n = e & 15, k = e >> 4;
        float v = W[(size_t)k*Hh + col0 + n];
        int ks = k >> 5, sub = (k >> 3) & 3, j = k & 7;
        int lane = n + (sub << 4);
        int byte = ((g*KS + ks) << 10) + (lane << 4) + (j << 1);
        *(f16*)(smem + byte) = (f16)v;
      }
    }
  }
  __syncthreads();

  const int lane = tid & 63;
  const int wv   = tid >> 6;
  const int rt   = wv & 1;         // row-tile within the 32-row half
  const int kh   = wv >> 1;        // K-half: which half of the reduction axis
  const int n    = lane & 15;
  const int kg   = lane >> 4;
  const int e8   = kg * 8;
  const int lrow = rt*16 + n;      // local row this lane LOADS (A-frag)
  const int grow = half*32 + lrow; // global batch row (x addressing)
  const int part = n & 3;
  const int rsel = n >> 2;
  const int srowl = rt*16 + 4*kg + rsel;

  const float* bfp = isL0 ? bf0 : bf1;
  const float* bcp = isL0 ? bc0 : bc1;
  const float bfv = bfp[col0 + n];
  const float bcv = bcp[col0 + n];

  const f16x8* ldsA = (const f16x8*)(smem + (size_t)lane*16);
  const size_t rdoff = (size_t)(kg>>1)*2048 + (size_t)half*1024
                     + (size_t)lrow*32 + (size_t)(kg&1)*16 + 4096;
  // partial-sum exchange: contiguous 16B per lane (conflict-free, v15)
  float* xchgF = (float*)(smem + 131072 + rt*1024 + lane*16);
  float* xchgC = (float*)(smem + 133120 + rt*1024 + lane*16);

  const int fl0 = FL0_U32 + (half*64)*16;
  const int fl1 = FL1_U32 + (half*64)*16;

  f32x4 cst = {0.f,0.f,0.f,0.f};

  if (isL0) {
    for (int t = 0; t < Ss; ++t) {
      f32x4 aF0={0.f,0.f,0.f,0.f}, aF1={0.f,0.f,0.f,0.f};
      f32x4 aC0={0.f,0.f,0.f,0.f}, aC1={0.f,0.f,0.f,0.f};
      // ---- x sub-range for this K-half wave, fully BEFORE the poll ----
      const float* xb = x + ((size_t)grow*Ss + (size_t)t)*Ff + (size_t)kh*256 + e8;
      float4 xv0[8], xv1[8];
      #pragma unroll
      for (int i = 0; i < 8; ++i) {
        xv0[i] = *(const float4*)(xb + 32*i);
        xv1[i] = *(const float4*)(xb + 32*i + 4);
      }
      #pragma unroll
      for (int i = 0; i < 8; ++i) {
        f16x8 a  = cvt8(xv0[i], xv1[i]);
        int ks = kh*8 + i;
        f16x8 bw = ldsA[(size_t)ks*64];
        f16x8 cw = ldsA[(size_t)(48 + ks)*64];
        if (i & 1){ aF1 = MFMA16(a, bw, aF1, 0,0,0); aC1 = MFMA16(a, cw, aC1, 0,0,0); }
        else      { aF0 = MFMA16(a, bw, aF0, 0,0,0); aC0 = MFMA16(a, cw, aC0, 0,0,0); }
      }
      // ---- wait (per-wave): h0(t-1) written ----
      pollwave(wsu, fl0, (unsigned)t);
      // ---- h0(t-1) = slot t: wave kh covers h k-steps [kh*16, kh*16+16) ----
      const char* hb = h0base + (size_t)t*SLOTB + rdoff + (size_t)kh*65536;
      f16x8 A0[8], A1[8];
      ISSUE8T(A0, hb,       hb+8192,  hb+16384, hb+24576);
      ISSUE8T(A1, hb+32768, hb+40960, hb+49152, hb+57344);
      WAITV(8); CONS8D(A0, 16 + kh*16, 48);
      WAITV(0); CONS8D(A1, 24 + kh*16, 48);
      // ---- K-half reduce: kh=1 -> LDS -> kh=0 adds; acts+store by kh=0 ----
      f32x4 pF = aF0 + aF1, pC = aC0 + aC1;
      if (kh == 1) { *(f32x4*)xchgF = pF; *(f32x4*)xchgC = pC; }
      __syncthreads();
      if (kh == 0) {
        pF += *(const f32x4*)xchgF;
        pC += *(const f32x4*)xchgC;
        unsigned cu[4];
        #pragma unroll
        for (int j = 0; j < 4; ++j) {
          float f  = sigm(pF[j] + bfv);
          float ct = tanhf_(pC[j] + bcv);
          cst[j] = f*cst[j] + (1.0f - f)*ct;
          union { _Float16 h; unsigned short u; } cv; cv.h = (f16)tanhf_(cst[j]);
          cu[j] = cv.u;
        }
        unsigned u01 = cu[0] | (cu[1] << 16);
        unsigned u23 = cu[2] | (cu[3] << 16);
        int sb = (kg << 4) + (part << 2);
        unsigned wsel[4];
        #pragma unroll
        for (int i = 0; i < 4; ++i) {
          unsigned w01 = __shfl(u01, sb + i, 64);
          unsigned w23 = __shfl(u23, sb + i, 64);
          unsigned w = (rsel < 2) ? w01 : w23;
          wsel[i] = (rsel & 1) ? (w >> 16) : (w & 0xffffu);
        }
        unsigned d0 = wsel[0] | (wsel[1] << 16);
        unsigned d1 = wsel[2] | (wsel[3] << 16);
        uint64_t dd = (uint64_t)d0 | ((uint64_t)d1 << 32);
        char* hd = h0base + (size_t)(t+1)*SLOTB + (size_t)lw*2048
                 + (size_t)half*1024 + (size_t)srowl*32 + (size_t)part*8;
        asm volatile("global_atomic_swap_x2 %0, %1, off" :: "v"(hd), "v"(dd) : "memory");
      }
      asm volatile("s_waitcnt vmcnt(0)" ::: "memory");
      __syncthreads();
      if (tid == 0) setflag(wsu + FL0_U32 + (half*64 + lw)*16, (unsigned)(t+1));
    }
  } else {
    for (int s = 0; s < Ss; ++s) {
      // ---- per-wave wait on OWN dependency only:
      //      kh=0 needs h0(s) (fl0>=s+1, usually ready); kh=1 needs h1(s-1)
      pollwave(wsu, kh == 0 ? fl0 : fl1, kh == 0 ? (unsigned)(s+1) : (unsigned)s);
      f32x4 aF0={0.f,0.f,0.f,0.f}, aF1={0.f,0.f,0.f,0.f};
      f32x4 aC0={0.f,0.f,0.f,0.f}, aC1={0.f,0.f,0.f,0.f};
      // wave kh=0: h0(s) = h0 slot s+1; kh=1: h1(s-1) = h1 slot s
      const char* hb = (kh == 0)
        ? h0base + (size_t)(s+1)*SLOTB + rdoff
        : h1base + (size_t)s*SLOTB + rdoff;
      f16x8 A0[8], A1[8], A2[8], A3[8];
      ISSUE8T(A0, hb,       hb+8192,  hb+16384, hb+24576);
      ISSUE8T(A1, hb+32768, hb+40960, hb+49152, hb+57344);
      ISSUE8T(A2, hb+65536, hb+73728, hb+81920, hb+90112);
      ISSUE8T(A3, hb+98304, hb+106496, hb+114688, hb+122880);
      {
        const int kb = kh*32;
        WAITV(24); CONS8D(A0, kb + 0,  64);
        WAITV(16); CONS8D(A1, kb + 8,  64);
        WAITV(8);  CONS8D(A2, kb + 16, 64);
        WAITV(0);  CONS8D(A3, kb + 24, 64);
      }
      // ---- K-half reduce + acts + store ----
      f32x4 pF = aF0 + aF1, pC = aC0 + aC1;
      if (kh == 1) { *(f32x4*)xchgF = pF; *(f32x4*)xchgC = pC; }
      __syncthreads();
      if (kh == 0) {
        pF += *(const f32x4*)xchgF;
        pC += *(const f32x4*)xchgC;
        unsigned cu[4];
        #pragma unroll
        for (int j = 0; j < 4; ++j) {
          float f  = sigm(pF[j] + bfv);
          float ct = tanhf_(pC[j] + bcv);
          cst[j] = f*cst[j] + (1.0f - f)*ct;
          union { _Float16 h; unsigned short u; } cv; cv.h = (f16)tanhf_(cst[j]);
          cu[j] = cv.u;
        }
        unsigned u01 = cu[0] | (cu[1] << 16);
        unsigned u23 = cu[2] | (cu[3] << 16);
        int sb = (kg << 4) + (part << 2);
        unsigned wsel[4];
        #pragma unroll
        for (int i = 0; i < 4; ++i) {
          unsigned w01 = __shfl(u01, sb + i, 64);
          unsigned w23 = __shfl(u23, sb + i, 64);
          unsigned w = (rsel < 2) ? w01 : w23;
          wsel[i] = (rsel & 1) ? (w >> 16) : (w & 0xffffu);
        }
        unsigned d0 = wsel[0] | (wsel[1] << 16);
        unsigned d1 = wsel[2] | (wsel[3] << 16);
        uint64_t dd = (uint64_t)d0 | ((uint64_t)d1 << 32);
        char* hd = h1base + (size_t)(s+1)*SLOTB + (size_t)lw*2048
                 + (size_t)half*1024 + (size_t)srowl*32 + (size_t)part*8;
        asm volatile("global_atomic_swap_x2 %0, %1, off" :: "v"(hd), "v"(dd) : "memory");
      }
      asm volatile("s_waitcnt vmcnt(0)" ::: "memory");
      __syncthreads();
      if (tid == 0) setflag(wsu + FL1_U32 + (half*64 + lw)*16, (unsigned)(s+1));
    }
  }

  // ---- final projection: out = h1(511) @ Wfc + bfc ----
  poll2(wsu, FL1_U32, (unsigned)Ss, FL1_U32 + 64*16, (unsigned)Ss, tid);
  if (tid < 128) {
    const char* fin = h1base + (size_t)Ss*SLOTB;   // slot 512 = h1(511)
    const int o = wid*2 + (tid & 1);
    const int b = tid >> 1;
    const char* rowp = fin + (size_t)(b>>5)*1024 + (size_t)(b&31)*32;
    float acc = bfc[o];
    for (int cg = 0; cg < 64; ++cg) {
      f16x8 lo, hi;
      asm volatile("global_load_dwordx4 %0, %2, off sc0 sc1\n\t"
                   "global_load_dwordx4 %1, %2, off offset:16 sc0 sc1\n\t"
                   "s_waitcnt vmcnt(0)"
                   : "=&v"(lo), "=&v"(hi) : "v"(rowp + (size_t)cg*2048) : "memory");
      #pragma unroll
      for (int i = 0; i < 8; ++i) {
        acc += (float)lo[i] * Wfc[(size_t)(cg*16 + i)*Oo + o];
        acc += (float)hi[i] * Wfc[(size_t)(cg*16 + 8 + i)*Oo + o];
      }
    }
    out[(size_t)b*Oo + o] = acc;
  }
}

extern "C" void kernel_launch(void* const* d_in, const int* in_sizes, int n_in,
                              void* d_out, int out_size, void* d_ws, size_t ws_size,
                              hipStream_t stream) {
  const float* x   = (const float*)d_in[0];
  const float* Wf0 = (const float*)d_in[1];
  const float* bf0 = (const float*)d_in[2];
  const float* Wc0 = (const float*)d_in[3];
  const float* bc0 = (const float*)d_in[4];
  const float* Wf1 = (const float*)d_in[5];
  const float* bf1 = (const float*)d_in[6];
  const float* Wc1 = (const float*)d_in[7];
  const float* bc1 = (const float*)d_in[8];
  const float* Wfc = (const float*)d_in[9];
  const float* bfc = (const float*)d_in[10];

  init_fresh<<<64, 256, 0, stream>>>(d_ws);
  janet_persistent<<<NWG, 256, 0, stream>>>(x, Wf0, bf0, Wc0, bc0,
                                            Wf1, bf1, Wc1, bc1, Wfc, bfc,
                                            (float*)d_out, d_ws);
}

// Round 17
// 2375.840 us; speedup vs baseline: 1.0639x; 1.0639x over previous
//
#include <hip/hip_runtime.h>
#include <stdint.h>

typedef _Float16 f16;
typedef _Float16 f16x8 __attribute__((ext_vector_type(8)));
typedef float    f32x4 __attribute__((ext_vector_type(4)));

#define Bm 64
#define Ss 512
#define Ff 512
#define Hh 1024
#define Oo 512
#define NWG 256          // {L0,L1} x {half0,half1} x 64 col-groups
#define HBh (Bm*Hh)
#define SLOTB (HBh*2)    // 131072 B per slot

// ---- flag layout: flags[layer][half][cg], 64B stride ----
#define FL0_U32 0                        // flags0[half*64+cg] at u32 16*idx
#define FL1_U32 4096                     // flags1[...] at byte 16384
// ---- write-once layout: slot k holds h(k-1); slot 0 = zeros ----
#define NSLOT 513
#define H0F_BYTE ((size_t)65536)
#define H1F_BYTE (H0F_BYTE + (size_t)NSLOT*SLOTB)
#define WSF_NEED (H1F_BYTE + (size_t)NSLOT*SLOTB)   // ~134.5 MB

#define MFMA16 __builtin_amdgcn_mfma_f32_16x16x32_f16

__device__ __forceinline__ float sigm(float x){ return 1.0f/(1.0f+__expf(-x)); }
__device__ __forceinline__ float tanhf_(float x){
  x = fminf(15.0f, fmaxf(-15.0f, x));
  float e = __expf(-2.0f*x);
  return (1.0f - e)/(1.0f + e);
}

__global__ void init_fresh(void* ws){
  const uint4 z = {0,0,0,0};
  int idx = blockIdx.x*blockDim.x + threadIdx.x;
  const int total = 4096 + 8192 + 8192;   // 64KB flags + h0 slot0 + h1 slot0
  for (int i = idx; i < total; i += gridDim.x*blockDim.x) {
    if (i < 4096)        ((uint4*)ws)[i] = z;
    else if (i < 12288)  ((uint4*)((char*)ws + H0F_BYTE))[i-4096]  = z;
    else                 ((uint4*)((char*)ws + H1F_BYTE))[i-12288] = z;
  }
}

// ---- sync primitives ----
__device__ __forceinline__ void setflag(unsigned* p, unsigned v){
  asm volatile("global_atomic_swap %0, %1, off" :: "v"(p), "v"(v) : "memory");
}

// poll one flag set with backoff (wave0 polls; barrier holds WG)
__device__ __forceinline__ void poll1(unsigned* wsu, int fb, unsigned tgt, int tid){
  if (tid < 64) {
    const unsigned* p0 = wsu + fb + 16*tid;
    for (;;) {
      unsigned v0;
      asm volatile("global_load_dword %0, %1, off sc0 sc1\n\t"
                   "s_waitcnt vmcnt(0)"
                   : "=&v"(v0) : "v"(p0) : "memory");
      if (__all(v0 >= tgt)) break;
      __builtin_amdgcn_s_sleep(1);
    }
  }
  asm volatile("s_waitcnt vmcnt(0)" ::: "memory");
  __builtin_amdgcn_sched_barrier(0);
  __syncthreads();
}

// poll two flag sets with backoff
__device__ __forceinline__ void poll2(unsigned* wsu, int fb0, unsigned tgt0,
                                      int fb1, unsigned tgt1, int tid){
  if (tid < 64) {
    const unsigned* p0 = wsu + fb0 + 16*tid;
    const unsigned* p1 = wsu + fb1 + 16*tid;
    for (;;) {
      unsigned v0, v1;
      asm volatile("global_load_dword %0, %2, off sc0 sc1\n\t"
                   "global_load_dword %1, %3, off sc0 sc1\n\t"
                   "s_waitcnt vmcnt(0)"
                   : "=&v"(v0), "=&v"(v1) : "v"(p0), "v"(p1) : "memory");
      if (__all((v0 >= tgt0) && (v1 >= tgt1))) break;
      __builtin_amdgcn_s_sleep(1);
    }
  }
  asm volatile("s_waitcnt vmcnt(0)" ::: "memory");
  __builtin_amdgcn_sched_barrier(0);
  __syncthreads();
}

// write-once-slot batch: 8 PLAIN CACHED 16B loads (L2 multicast across the
// same-(layer,half) WGs per XCD); pointers pre-offset +4096; each pointer
// serves a ks pair via offsets {-4096, 0}.
#define ISSUE8T(A, P0, P1, P2, P3) asm volatile( \
  "global_load_dwordx4 %0, %8, off offset:-4096\n\t" \
  "global_load_dwordx4 %1, %8, off\n\t" \
  "global_load_dwordx4 %2, %9, off offset:-4096\n\t" \
  "global_load_dwordx4 %3, %9, off\n\t" \
  "global_load_dwordx4 %4, %10, off offset:-4096\n\t" \
  "global_load_dwordx4 %5, %10, off\n\t" \
  "global_load_dwordx4 %6, %11, off offset:-4096\n\t" \
  "global_load_dwordx4 %7, %11, off" \
  : "=&v"(A[0]), "=&v"(A[1]), "=&v"(A[2]), "=&v"(A[3]), \
    "=&v"(A[4]), "=&v"(A[5]), "=&v"(A[6]), "=&v"(A[7]) \
  : "v"(P0), "v"(P1), "v"(P2), "v"(P3) : "memory")

#define WAITV(N) do{ asm volatile("s_waitcnt vmcnt(" #N ")" ::: "memory"); \
                     __builtin_amdgcn_sched_barrier(0x106); }while(0)

// 8 k-steps of DUAL-gate MFMA; F weights at ks, C weights at KSC+ks
#define CONS8D(Aarr, KSB, KSC) do{ \
  _Pragma("unroll") \
  for (int j = 0; j < 8; ++j){ \
    f16x8 bw = ldsA[(size_t)((KSB)+j)*64]; \
    f16x8 cw = ldsA[(size_t)((KSC)+(KSB)+j)*64]; \
    if (j & 1){ aF1 = MFMA16(Aarr[j], bw, aF1, 0,0,0); aC1 = MFMA16(Aarr[j], cw, aC1, 0,0,0); } \
    else      { aF0 = MFMA16(Aarr[j], bw, aF0, 0,0,0); aC0 = MFMA16(Aarr[j], cw, aC0, 0,0,0); } \
  } \
}while(0)

__device__ __forceinline__ f16x8 cvt8(float4 v0, float4 v1){
  f16x8 a;
  a[0]=v0.x; a[1]=v0.y; a[2]=v0.z; a[3]=v0.w;
  a[4]=v1.x; a[5]=v1.y; a[6]=v1.z; a[7]=v1.w;
  return a;
}

__global__ __launch_bounds__(256,1) void janet_persistent(
    const float* __restrict__ x,
    const float* __restrict__ Wf0, const float* __restrict__ bf0,
    const float* __restrict__ Wc0, const float* __restrict__ bc0,
    const float* __restrict__ Wf1, const float* __restrict__ bf1,
    const float* __restrict__ Wc1, const float* __restrict__ bc1,
    const float* __restrict__ Wfc, const float* __restrict__ bfc,
    float* __restrict__ out, void* __restrict__ ws)
{
  __shared__ __align__(16) unsigned char smem[135168];   // 128KB W + 4KB xchg
  __builtin_amdgcn_fence(__ATOMIC_ACQUIRE, "agent");     // write-once scheme

  unsigned* wsu = (unsigned*)ws;
  char* h0base = (char*)ws + H0F_BYTE;
  char* h1base = (char*)ws + H1F_BYTE;

  const int wid  = blockIdx.x;
  const int tid  = threadIdx.x;
  const bool isL0 = (wid < 128);
  const int half = (wid >> 6) & 1;
  const int lw   = wid & 63;           // col-group
  const int col0 = lw * 16;
  const int K    = isL0 ? (Ff + Hh) : (2*Hh);   // 1536 / 2048
  const int KS   = K >> 5;                      // 48 / 64

  // ---- stage weights into LDS in MFMA B-fragment order [gate][ks][lane] ----
  {
    const float* Wg[2] = { isL0 ? Wf0 : Wf1, isL0 ? Wc0 : Wc1 };
    for (int g = 0; g < 2; ++g) {
      const float* W = Wg[g];
      for (int e = tid; e < 16*K; e += 256) {
        int n = e & 15, k = e >> 4;
        float v = W[(size_t)k*Hh + col0 + n];
        int ks = k >> 5, sub = (k >> 3) & 3, j = k & 7;
        int lane = n + (sub << 4);
        int byte = ((g*KS + ks) << 10) + (lane << 4) + (j << 1);
        *(f16*)(smem + byte) = (f16)v;
      }
    }
  }
  __syncthreads();

  const int lane = tid & 63;
  const int wv   = tid >> 6;
  const int rt   = wv & 1;         // row-tile within the 32-row half
  const int kh   = wv >> 1;        // K-half of the reduction axis
  const int n    = lane & 15;
  const int kg   = lane >> 4;
  const int e8   = kg * 8;
  const int lrow = rt*16 + n;      // local row this lane LOADS (A-frag)
  const int grow = half*32 + lrow; // global batch row (x addressing)
  const int part = n & 3;
  const int rsel = n >> 2;
  const int srowl = rt*16 + 4*kg + rsel;

  const float* bfp = isL0 ? bf0 : bf1;
  const float* bcp = isL0 ? bc0 : bc1;
  const float bfv = bfp[col0 + n];
  const float bcv = bcp[col0 + n];

  const f16x8* ldsA = (const f16x8*)(smem + (size_t)lane*16);
  const size_t rdoff = (size_t)(kg>>1)*2048 + (size_t)half*1024
                     + (size_t)lrow*32 + (size_t)(kg&1)*16 + 4096;
  // partial-sum exchange: contiguous 16B per lane (conflict-free, v15)
  float* xchgF = (float*)(smem + 131072 + rt*1024 + lane*16);
  float* xchgC = (float*)(smem + 133120 + rt*1024 + lane*16);

  const int fl0 = FL0_U32 + (half*64)*16;
  const int fl1 = FL1_U32 + (half*64)*16;

  f32x4 cst = {0.f,0.f,0.f,0.f};

  if (isL0) {
    for (int t = 0; t < Ss; ++t) {
      f32x4 aF0={0.f,0.f,0.f,0.f}, aF1={0.f,0.f,0.f,0.f};
      f32x4 aC0={0.f,0.f,0.f,0.f}, aC1={0.f,0.f,0.f,0.f};
      // ---- x sub-range for this K-half wave, fully BEFORE the poll ----
      const float* xb = x + ((size_t)grow*Ss + (size_t)t)*Ff + (size_t)kh*256 + e8;
      float4 xv0[8], xv1[8];
      #pragma unroll
      for (int i = 0; i < 8; ++i) {
        xv0[i] = *(const float4*)(xb + 32*i);
        xv1[i] = *(const float4*)(xb + 32*i + 4);
      }
      #pragma unroll
      for (int i = 0; i < 8; ++i) {
        f16x8 a  = cvt8(xv0[i], xv1[i]);
        int ks = kh*8 + i;
        f16x8 bw = ldsA[(size_t)ks*64];
        f16x8 cw = ldsA[(size_t)(48 + ks)*64];
        if (i & 1){ aF1 = MFMA16(a, bw, aF1, 0,0,0); aC1 = MFMA16(a, cw, aC1, 0,0,0); }
        else      { aF0 = MFMA16(a, bw, aF0, 0,0,0); aC0 = MFMA16(a, cw, aC0, 0,0,0); }
      }
      // ---- wait: h0(t-1) written (write-once: no WAR term) ----
      poll1(wsu, fl0, (unsigned)t, tid);
      // ---- h0(t-1) = slot t: wave kh covers h k-steps [kh*16, kh*16+16) ----
      const char* hb = h0base + (size_t)t*SLOTB + rdoff + (size_t)kh*65536;
      f16x8 A0[8], A1[8];
      ISSUE8T(A0, hb,       hb+8192,  hb+16384, hb+24576);
      ISSUE8T(A1, hb+32768, hb+40960, hb+49152, hb+57344);
      WAITV(8); CONS8D(A0, 16 + kh*16, 48);
      WAITV(0); CONS8D(A1, 24 + kh*16, 48);
      // ---- K-half reduce: kh=1 -> LDS -> kh=0 adds; acts+store by kh=0 ----
      f32x4 pF = aF0 + aF1, pC = aC0 + aC1;
      if (kh == 1) { *(f32x4*)xchgF = pF; *(f32x4*)xchgC = pC; }
      __syncthreads();
      if (kh == 0) {
        pF += *(const f32x4*)xchgF;
        pC += *(const f32x4*)xchgC;
        unsigned cu[4];
        #pragma unroll
        for (int j = 0; j < 4; ++j) {
          float f  = sigm(pF[j] + bfv);
          float ct = tanhf_(pC[j] + bcv);
          cst[j] = f*cst[j] + (1.0f - f)*ct;
          union { _Float16 h; unsigned short u; } cv; cv.h = (f16)tanhf_(cst[j]);
          cu[j] = cv.u;
        }
        unsigned u01 = cu[0] | (cu[1] << 16);
        unsigned u23 = cu[2] | (cu[3] << 16);
        int sb = (kg << 4) + (part << 2);
        unsigned wsel[4];
        #pragma unroll
        for (int i = 0; i < 4; ++i) {
          unsigned w01 = __shfl(u01, sb + i, 64);
          unsigned w23 = __shfl(u23, sb + i, 64);
          unsigned w = (rsel < 2) ? w01 : w23;
          wsel[i] = (rsel & 1) ? (w >> 16) : (w & 0xffffu);
        }
        unsigned d0 = wsel[0] | (wsel[1] << 16);
        unsigned d1 = wsel[2] | (wsel[3] << 16);
        uint64_t dd = (uint64_t)d0 | ((uint64_t)d1 << 32);
        char* hd = h0base + (size_t)(t+1)*SLOTB + (size_t)lw*2048
                 + (size_t)half*1024 + (size_t)srowl*32 + (size_t)part*8;
        asm volatile("global_atomic_swap_x2 %0, %1, off" :: "v"(hd), "v"(dd) : "memory");
      }
      asm volatile("s_waitcnt vmcnt(0)" ::: "memory");
      __syncthreads();
      if (tid == 0) setflag(wsu + FL0_U32 + (half*64 + lw)*16, (unsigned)(t+1));
    }
  } else {
    // initial authorization for s=0 prework: h0(0) = slot 1 written
    poll1(wsu, fl0, 1u, tid);
    for (int s = 0; s < Ss; ++s) {
      f32x4 aF0={0.f,0.f,0.f,0.f}, aF1={0.f,0.f,0.f,0.f};
      f32x4 aC0={0.f,0.f,0.f,0.f}, aC1={0.f,0.f,0.f,0.f};
      // ---- PREWORK (off critical path): h0(s) chunk = slot s+1,
      //      ks [kh*16, kh*16+16) — authorized by previous step's lookahead
      const char* hbA = h0base + (size_t)(s+1)*SLOTB + rdoff + (size_t)kh*65536;
      f16x8 A0[8], A1[8];
      ISSUE8T(A0, hbA,       hbA+8192,  hbA+16384, hbA+24576);
      ISSUE8T(A1, hbA+32768, hbA+40960, hbA+49152, hbA+57344);
      WAITV(8); CONS8D(A0, kh*16,     64);
      WAITV(0); CONS8D(A1, kh*16 + 8, 64);
      // ---- serial wait: fl1>=s; lookahead fl0>=min(s+2,512) for next prework ----
      unsigned f0tgt = (unsigned)(s+2 > Ss ? Ss : s+2);
      poll2(wsu, fl0, f0tgt, fl1, (unsigned)s, tid);
      // ---- h1(s-1) chunk = slot s, ks [32+kh*16, +16) ----
      const char* hbB = h1base + (size_t)s*SLOTB + rdoff + (size_t)kh*65536;
      f16x8 B0[8], B1[8];
      ISSUE8T(B0, hbB,       hbB+8192,  hbB+16384, hbB+24576);
      ISSUE8T(B1, hbB+32768, hbB+40960, hbB+49152, hbB+57344);
      WAITV(8); CONS8D(B0, 32 + kh*16,     64);
      WAITV(0); CONS8D(B1, 32 + kh*16 + 8, 64);
      // ---- K-half reduce: kh=0 writes; kh=1 (actor, holds cst) acts+stores ----
      f32x4 pF = aF0 + aF1, pC = aC0 + aC1;
      if (kh == 0) { *(f32x4*)xchgF = pF; *(f32x4*)xchgC = pC; }
      __syncthreads();
      if (kh == 1) {
        pF += *(const f32x4*)xchgF;
        pC += *(const f32x4*)xchgC;
        unsigned cu[4];
        #pragma unroll
        for (int j = 0; j < 4; ++j) {
          float f  = sigm(pF[j] + bfv);
          float ct = tanhf_(pC[j] + bcv);
          cst[j] = f*cst[j] + (1.0f - f)*ct;
          union { _Float16 h; unsigned short u; } cv; cv.h = (f16)tanhf_(cst[j]);
          cu[j] = cv.u;
        }
        unsigned u01 = cu[0] | (cu[1] << 16);
        unsigned u23 = cu[2] | (cu[3] << 16);
        int sb = (kg << 4) + (part << 2);
        unsigned wsel[4];
        #pragma unroll
        for (int i = 0; i < 4; ++i) {
          unsigned w01 = __shfl(u01, sb + i, 64);
          unsigned w23 = __shfl(u23, sb + i, 64);
          unsigned w = (rsel < 2) ? w01 : w23;
          wsel[i] = (rsel & 1) ? (w >> 16) : (w & 0xffffu);
        }
        unsigned d0 = wsel[0] | (wsel[1] << 16);
        unsigned d1 = wsel[2] | (wsel[3] << 16);
        uint64_t dd = (uint64_t)d0 | ((uint64_t)d1 << 32);
        char* hd = h1base + (size_t)(s+1)*SLOTB + (size_t)lw*2048
                 + (size_t)half*1024 + (size_t)srowl*32 + (size_t)part*8;
        asm volatile("global_atomic_swap_x2 %0, %1, off" :: "v"(hd), "v"(dd) : "memory");
      }
      asm volatile("s_waitcnt vmcnt(0)" ::: "memory");
      __syncthreads();
      if (tid == 0) setflag(wsu + FL1_U32 + (half*64 + lw)*16, (unsigned)(s+1));
    }
  }

  // ---- final projection: out = h1(511) @ Wfc + bfc ----
  poll2(wsu, FL1_U32, (unsigned)Ss, FL1_U32 + 64*16, (unsigned)Ss, tid);
  if (tid < 128) {
    const char* fin = h1base + (size_t)Ss*SLOTB;   // slot 512 = h1(511)
    const int o = wid*2 + (tid & 1);
    const int b = tid >> 1;
    const char* rowp = fin + (size_t)(b>>5)*1024 + (size_t)(b&31)*32;
    float acc = bfc[o];
    for (int cg = 0; cg < 64; ++cg) {
      f16x8 lo, hi;
      asm volatile("global_load_dwordx4 %0, %2, off sc0 sc1\n\t"
                   "global_load_dwordx4 %1, %2, off offset:16 sc0 sc1\n\t"
                   "s_waitcnt vmcnt(0)"
                   : "=&v"(lo), "=&v"(hi) : "v"(rowp + (size_t)cg*2048) : "memory");
      #pragma unroll
      for (int i = 0; i < 8; ++i) {
        acc += (float)lo[i] * Wfc[(size_t)(cg*16 + i)*Oo + o];
        acc += (float)hi[i] * Wfc[(size_t)(cg*16 + 8 + i)*Oo + o];
      }
    }
    out[(size_t)b*Oo + o] = acc;
  }
}

extern "C" void kernel_launch(void* const* d_in, const int* in_sizes, int n_in,
                              void* d_out, int out_size, void* d_ws, size_t ws_size,
                              hipStream_t stream) {
  const float* x   = (const float*)d_in[0];
  const float* Wf0 = (const float*)d_in[1];
  const float* bf0 = (const float*)d_in[2];
  const float* Wc0 = (const float*)d_in[3];
  const float* bc0 = (const float*)d_in[4];
  const float* Wf1 = (const float*)d_in[5];
  const float* bf1 = (const float*)d_in[6];
  const float* Wc1 = (const float*)d_in[7];
  const float* bc1 = (const float*)d_in[8];
  const float* Wfc = (const float*)d_in[9];
  const float* bfc = (const float*)d_in[10];

  init_fresh<<<64, 256, 0, stream>>>(d_ws);
  janet_persistent<<<NWG, 256, 0, stream>>>(x, Wf0, bf0, Wc0, bc0,
                                            Wf1, bf1, Wc1, bc1, Wfc, bfc,
                                            (float*)d_out, d_ws);
}

// Round 18
// 2345.665 us; speedup vs baseline: 1.0776x; 1.0129x over previous
//
#include <hip/hip_runtime.h>
#include <stdint.h>

typedef _Float16 f16;
typedef _Float16 f16x8 __attribute__((ext_vector_type(8)));
typedef float    f32x4 __attribute__((ext_vector_type(4)));

#define Bm 64
#define Ss 512
#define Ff 512
#define Hh 1024
#define Oo 512
#define NWG 256          // {L0,L1} x {half0,half1} x 64 col-groups
#define HBh (Bm*Hh)
#define SLOTB (HBh*2)    // 131072 B per slot

// ---- flag layout: flags[layer][half][cg], 64B stride ----
#define FL0_U32 0                        // flags0[half*64+cg] at u32 16*idx
#define FL1_U32 4096                     // flags1[...] at byte 16384
// ---- write-once layout: slot k holds h(k-1); slot 0 = zeros ----
#define NSLOT 513
#define H0F_BYTE ((size_t)65536)
#define H1F_BYTE (H0F_BYTE + (size_t)NSLOT*SLOTB)
#define WSF_NEED (H1F_BYTE + (size_t)NSLOT*SLOTB)   // ~134.5 MB

#define MFMA16 __builtin_amdgcn_mfma_f32_16x16x32_f16

__device__ __forceinline__ float sigm(float x){ return 1.0f/(1.0f+__expf(-x)); }
__device__ __forceinline__ float tanhf_(float x){
  x = fminf(15.0f, fmaxf(-15.0f, x));
  float e = __expf(-2.0f*x);
  return (1.0f - e)/(1.0f + e);
}

__global__ void init_fresh(void* ws){
  const uint4 z = {0,0,0,0};
  int idx = blockIdx.x*blockDim.x + threadIdx.x;
  const int total = 4096 + 8192 + 8192;   // 64KB flags + h0 slot0 + h1 slot0
  for (int i = idx; i < total; i += gridDim.x*blockDim.x) {
    if (i < 4096)        ((uint4*)ws)[i] = z;
    else if (i < 12288)  ((uint4*)((char*)ws + H0F_BYTE))[i-4096]  = z;
    else                 ((uint4*)((char*)ws + H1F_BYTE))[i-12288] = z;
  }
}

// ---- sync primitives ----
__device__ __forceinline__ void setflag(unsigned* p, unsigned v){
  asm volatile("global_atomic_swap %0, %1, off" :: "v"(p), "v"(v) : "memory");
}

// poll one flag set with backoff (wave0 polls; barrier holds WG)
__device__ __forceinline__ void poll1(unsigned* wsu, int fb, unsigned tgt, int tid){
  if (tid < 64) {
    const unsigned* p0 = wsu + fb + 16*tid;
    for (;;) {
      unsigned v0;
      asm volatile("global_load_dword %0, %1, off sc0 sc1\n\t"
                   "s_waitcnt vmcnt(0)"
                   : "=&v"(v0) : "v"(p0) : "memory");
      if (__all(v0 >= tgt)) break;
      __builtin_amdgcn_s_sleep(1);
    }
  }
  asm volatile("s_waitcnt vmcnt(0)" ::: "memory");
  __builtin_amdgcn_sched_barrier(0);
  __syncthreads();
}

// poll two flag sets with backoff
__device__ __forceinline__ void poll2(unsigned* wsu, int fb0, unsigned tgt0,
                                      int fb1, unsigned tgt1, int tid){
  if (tid < 64) {
    const unsigned* p0 = wsu + fb0 + 16*tid;
    const unsigned* p1 = wsu + fb1 + 16*tid;
    for (;;) {
      unsigned v0, v1;
      asm volatile("global_load_dword %0, %2, off sc0 sc1\n\t"
                   "global_load_dword %1, %3, off sc0 sc1\n\t"
                   "s_waitcnt vmcnt(0)"
                   : "=&v"(v0), "=&v"(v1) : "v"(p0), "v"(p1) : "memory");
      if (__all((v0 >= tgt0) && (v1 >= tgt1))) break;
      __builtin_amdgcn_s_sleep(1);
    }
  }
  asm volatile("s_waitcnt vmcnt(0)" ::: "memory");
  __builtin_amdgcn_sched_barrier(0);
  __syncthreads();
}

// write-once-slot batch: 8 PLAIN CACHED 16B loads (L2 multicast within the
// group's XCD pair); pointers pre-offset +4096; each serves a ks pair via
// offsets {-4096, 0}.
#define ISSUE8T(A, P0, P1, P2, P3) asm volatile( \
  "global_load_dwordx4 %0, %8, off offset:-4096\n\t" \
  "global_load_dwordx4 %1, %8, off\n\t" \
  "global_load_dwordx4 %2, %9, off offset:-4096\n\t" \
  "global_load_dwordx4 %3, %9, off\n\t" \
  "global_load_dwordx4 %4, %10, off offset:-4096\n\t" \
  "global_load_dwordx4 %5, %10, off\n\t" \
  "global_load_dwordx4 %6, %11, off offset:-4096\n\t" \
  "global_load_dwordx4 %7, %11, off" \
  : "=&v"(A[0]), "=&v"(A[1]), "=&v"(A[2]), "=&v"(A[3]), \
    "=&v"(A[4]), "=&v"(A[5]), "=&v"(A[6]), "=&v"(A[7]) \
  : "v"(P0), "v"(P1), "v"(P2), "v"(P3) : "memory")

#define WAITV(N) do{ asm volatile("s_waitcnt vmcnt(" #N ")" ::: "memory"); \
                     __builtin_amdgcn_sched_barrier(0x106); }while(0)

// 8 k-steps of DUAL-gate MFMA; F weights at ks, C weights at KSC+ks
#define CONS8D(Aarr, KSB, KSC) do{ \
  _Pragma("unroll") \
  for (int j = 0; j < 8; ++j){ \
    f16x8 bw = ldsA[(size_t)((KSB)+j)*64]; \
    f16x8 cw = ldsA[(size_t)((KSC)+(KSB)+j)*64]; \
    if (j & 1){ aF1 = MFMA16(Aarr[j], bw, aF1, 0,0,0); aC1 = MFMA16(Aarr[j], cw, aC1, 0,0,0); } \
    else      { aF0 = MFMA16(Aarr[j], bw, aF0, 0,0,0); aC0 = MFMA16(Aarr[j], cw, aC0, 0,0,0); } \
  } \
}while(0)

__device__ __forceinline__ f16x8 cvt8(float4 v0, float4 v1){
  f16x8 a;
  a[0]=v0.x; a[1]=v0.y; a[2]=v0.z; a[3]=v0.w;
  a[4]=v1.x; a[5]=v1.y; a[6]=v1.z; a[7]=v1.w;
  return a;
}

__global__ __launch_bounds__(256,1) void janet_persistent(
    const float* __restrict__ x,
    const float* __restrict__ Wf0, const float* __restrict__ bf0,
    const float* __restrict__ Wc0, const float* __restrict__ bc0,
    const float* __restrict__ Wf1, const float* __restrict__ bf1,
    const float* __restrict__ Wc1, const float* __restrict__ bc1,
    const float* __restrict__ Wfc, const float* __restrict__ bfc,
    float* __restrict__ out, void* __restrict__ ws)
{
  __shared__ __align__(16) unsigned char smem[135168];   // 128KB W + 4KB xchg
  __builtin_amdgcn_fence(__ATOMIC_ACQUIRE, "agent");     // write-once scheme

  unsigned* wsu = (unsigned*)ws;
  char* h0base = (char*)ws + H0F_BYTE;
  char* h1base = (char*)ws + H1F_BYTE;

  // ---- XCD-pair pinning: with the typical blockIdx%8 -> XCD round-robin,
  // group g = (b&7)>>1 (L0h0,L0h1,L1h0,L1h1) lands entirely on XCDs {2g,2g+1},
  // so each group's h all-gather is served by 2 local L2s instead of far LLC.
  // Pure perf heuristic: any other dispatch mapping is still correct.
  const int bphys = blockIdx.x;
  const int grp  = (bphys & 7) >> 1;
  const int lw   = ((bphys >> 3) << 1) | (bphys & 1);   // col-group 0..63
  const bool isL0 = (grp < 2);
  const int half = grp & 1;
  const int tid  = threadIdx.x;
  const int col0 = lw * 16;
  const int K    = isL0 ? (Ff + Hh) : (2*Hh);   // 1536 / 2048
  const int KS   = K >> 5;                      // 48 / 64

  // ---- stage weights into LDS in MFMA B-fragment order [gate][ks][lane] ----
  {
    const float* Wg[2] = { isL0 ? Wf0 : Wf1, isL0 ? Wc0 : Wc1 };
    for (int g = 0; g < 2; ++g) {
      const float* W = Wg[g];
      for (int e = tid; e < 16*K; e += 256) {
        int n = e & 15, k = e >> 4;
        float v = W[(size_t)k*Hh + col0 + n];
        int ks = k >> 5, sub = (k >> 3) & 3, j = k & 7;
        int lane = n + (sub << 4);
        int byte = ((g*KS + ks) << 10) + (lane << 4) + (j << 1);
        *(f16*)(smem + byte) = (f16)v;
      }
    }
  }
  __syncthreads();

  const int lane = tid & 63;
  const int wv   = tid >> 6;
  const int rt   = wv & 1;         // row-tile within the 32-row half
  const int kh   = wv >> 1;        // K-half of the reduction axis
  const int n    = lane & 15;
  const int kg   = lane >> 4;
  const int e8   = kg * 8;
  const int lrow = rt*16 + n;      // local row this lane LOADS (A-frag)
  const int grow = half*32 + lrow; // global batch row (x addressing)
  const int part = n & 3;
  const int rsel = n >> 2;
  const int srowl = rt*16 + 4*kg + rsel;

  const float* bfp = isL0 ? bf0 : bf1;
  const float* bcp = isL0 ? bc0 : bc1;
  const float bfv = bfp[col0 + n];
  const float bcv = bcp[col0 + n];

  const f16x8* ldsA = (const f16x8*)(smem + (size_t)lane*16);
  const size_t rdoff = (size_t)(kg>>1)*2048 + (size_t)half*1024
                     + (size_t)lrow*32 + (size_t)(kg&1)*16 + 4096;
  // partial-sum exchange: contiguous 16B per lane (conflict-free, v15)
  float* xchgF = (float*)(smem + 131072 + rt*1024 + lane*16);
  float* xchgC = (float*)(smem + 133120 + rt*1024 + lane*16);

  const int fl0 = FL0_U32 + (half*64)*16;
  const int fl1 = FL1_U32 + (half*64)*16;

  f32x4 cst = {0.f,0.f,0.f,0.f};

  if (isL0) {
    for (int t = 0; t < Ss; ++t) {
      f32x4 aF0={0.f,0.f,0.f,0.f}, aF1={0.f,0.f,0.f,0.f};
      f32x4 aC0={0.f,0.f,0.f,0.f}, aC1={0.f,0.f,0.f,0.f};
      // ---- x sub-range for this K-half wave, fully BEFORE the poll ----
      const float* xb = x + ((size_t)grow*Ss + (size_t)t)*Ff + (size_t)kh*256 + e8;
      float4 xv0[8], xv1[8];
      #pragma unroll
      for (int i = 0; i < 8; ++i) {
        xv0[i] = *(const float4*)(xb + 32*i);
        xv1[i] = *(const float4*)(xb + 32*i + 4);
      }
      #pragma unroll
      for (int i = 0; i < 8; ++i) {
        f16x8 a  = cvt8(xv0[i], xv1[i]);
        int ks = kh*8 + i;
        f16x8 bw = ldsA[(size_t)ks*64];
        f16x8 cw = ldsA[(size_t)(48 + ks)*64];
        if (i & 1){ aF1 = MFMA16(a, bw, aF1, 0,0,0); aC1 = MFMA16(a, cw, aC1, 0,0,0); }
        else      { aF0 = MFMA16(a, bw, aF0, 0,0,0); aC0 = MFMA16(a, cw, aC0, 0,0,0); }
      }
      // ---- wait: h0(t-1) written (write-once: no WAR term) ----
      poll1(wsu, fl0, (unsigned)t, tid);
      // ---- h0(t-1) = slot t: wave kh covers h k-steps [kh*16, kh*16+16) ----
      const char* hb = h0base + (size_t)t*SLOTB + rdoff + (size_t)kh*65536;
      f16x8 A0[8], A1[8];
      ISSUE8T(A0, hb,       hb+8192,  hb+16384, hb+24576);
      ISSUE8T(A1, hb+32768, hb+40960, hb+49152, hb+57344);
      WAITV(8); CONS8D(A0, 16 + kh*16, 48);
      WAITV(0); CONS8D(A1, 24 + kh*16, 48);
      // ---- K-half reduce: kh=1 -> LDS -> kh=0 adds; acts+store by kh=0 ----
      f32x4 pF = aF0 + aF1, pC = aC0 + aC1;
      if (kh == 1) { *(f32x4*)xchgF = pF; *(f32x4*)xchgC = pC; }
      __syncthreads();
      if (kh == 0) {
        pF += *(const f32x4*)xchgF;
        pC += *(const f32x4*)xchgC;
        unsigned cu[4];
        #pragma unroll
        for (int j = 0; j < 4; ++j) {
          float f  = sigm(pF[j] + bfv);
          float ct = tanhf_(pC[j] + bcv);
          cst[j] = f*cst[j] + (1.0f - f)*ct;
          union { _Float16 h; unsigned short u; } cv; cv.h = (f16)tanhf_(cst[j]);
          cu[j] = cv.u;
        }
        unsigned u01 = cu[0] | (cu[1] << 16);
        unsigned u23 = cu[2] | (cu[3] << 16);
        int sb = (kg << 4) + (part << 2);
        unsigned wsel[4];
        #pragma unroll
        for (int i = 0; i < 4; ++i) {
          unsigned w01 = __shfl(u01, sb + i, 64);
          unsigned w23 = __shfl(u23, sb + i, 64);
          unsigned w = (rsel < 2) ? w01 : w23;
          wsel[i] = (rsel & 1) ? (w >> 16) : (w & 0xffffu);
        }
        unsigned d0 = wsel[0] | (wsel[1] << 16);
        unsigned d1 = wsel[2] | (wsel[3] << 16);
        uint64_t dd = (uint64_t)d0 | ((uint64_t)d1 << 32);
        char* hd = h0base + (size_t)(t+1)*SLOTB + (size_t)lw*2048
                 + (size_t)half*1024 + (size_t)srowl*32 + (size_t)part*8;
        asm volatile("global_atomic_swap_x2 %0, %1, off" :: "v"(hd), "v"(dd) : "memory");
      }
      asm volatile("s_waitcnt vmcnt(0)" ::: "memory");
      __syncthreads();
      if (tid == 0) setflag(wsu + FL0_U32 + (half*64 + lw)*16, (unsigned)(t+1));
    }
  } else {
    // initial authorization for s=0 prework: h0(0) = slot 1 written
    poll1(wsu, fl0, 1u, tid);
    for (int s = 0; s < Ss; ++s) {
      f32x4 aF0={0.f,0.f,0.f,0.f}, aF1={0.f,0.f,0.f,0.f};
      f32x4 aC0={0.f,0.f,0.f,0.f}, aC1={0.f,0.f,0.f,0.f};
      // ---- PREWORK (off critical path): h0(s) chunk = slot s+1 ----
      const char* hbA = h0base + (size_t)(s+1)*SLOTB + rdoff + (size_t)kh*65536;
      f16x8 A0[8], A1[8];
      ISSUE8T(A0, hbA,       hbA+8192,  hbA+16384, hbA+24576);
      ISSUE8T(A1, hbA+32768, hbA+40960, hbA+49152, hbA+57344);
      WAITV(8); CONS8D(A0, kh*16,     64);
      WAITV(0); CONS8D(A1, kh*16 + 8, 64);
      // ---- serial wait: fl1>=s; lookahead fl0>=min(s+2,512) ----
      unsigned f0tgt = (unsigned)(s+2 > Ss ? Ss : s+2);
      poll2(wsu, fl0, f0tgt, fl1, (unsigned)s, tid);
      // ---- h1(s-1) chunk = slot s, ks [32+kh*16, +16) ----
      const char* hbB = h1base + (size_t)s*SLOTB + rdoff + (size_t)kh*65536;
      f16x8 B0[8], B1[8];
      ISSUE8T(B0, hbB,       hbB+8192,  hbB+16384, hbB+24576);
      ISSUE8T(B1, hbB+32768, hbB+40960, hbB+49152, hbB+57344);
      WAITV(8); CONS8D(B0, 32 + kh*16,     64);
      WAITV(0); CONS8D(B1, 32 + kh*16 + 8, 64);
      // ---- K-half reduce: kh=0 writes; kh=1 (actor, holds cst) acts+stores ----
      f32x4 pF = aF0 + aF1, pC = aC0 + aC1;
      if (kh == 0) { *(f32x4*)xchgF = pF; *(f32x4*)xchgC = pC; }
      __syncthreads();
      if (kh == 1) {
        pF += *(const f32x4*)xchgF;
        pC += *(const f32x4*)xchgC;
        unsigned cu[4];
        #pragma unroll
        for (int j = 0; j < 4; ++j) {
          float f  = sigm(pF[j] + bfv);
          float ct = tanhf_(pC[j] + bcv);
          cst[j] = f*cst[j] + (1.0f - f)*ct;
          union { _Float16 h; unsigned short u; } cv; cv.h = (f16)tanhf_(cst[j]);
          cu[j] = cv.u;
        }
        unsigned u01 = cu[0] | (cu[1] << 16);
        unsigned u23 = cu[2] | (cu[3] << 16);
        int sb = (kg << 4) + (part << 2);
        unsigned wsel[4];
        #pragma unroll
        for (int i = 0; i < 4; ++i) {
          unsigned w01 = __shfl(u01, sb + i, 64);
          unsigned w23 = __shfl(u23, sb + i, 64);
          unsigned w = (rsel < 2) ? w01 : w23;
          wsel[i] = (rsel & 1) ? (w >> 16) : (w & 0xffffu);
        }
        unsigned d0 = wsel[0] | (wsel[1] << 16);
        unsigned d1 = wsel[2] | (wsel[3] << 16);
        uint64_t dd = (uint64_t)d0 | ((uint64_t)d1 << 32);
        char* hd = h1base + (size_t)(s+1)*SLOTB + (size_t)lw*2048
                 + (size_t)half*1024 + (size_t)srowl*32 + (size_t)part*8;
        asm volatile("global_atomic_swap_x2 %0, %1, off" :: "v"(hd), "v"(dd) : "memory");
      }
      asm volatile("s_waitcnt vmcnt(0)" ::: "memory");
      __syncthreads();
      if (tid == 0) setflag(wsu + FL1_U32 + (half*64 + lw)*16, (unsigned)(s+1));
    }
  }

  // ---- final projection: out = h1(511) @ Wfc + bfc ----
  poll2(wsu, FL1_U32, (unsigned)Ss, FL1_U32 + 64*16, (unsigned)Ss, tid);
  if (tid < 128) {
    const char* fin = h1base + (size_t)Ss*SLOTB;   // slot 512 = h1(511)
    const int o = bphys*2 + (tid & 1);
    const int b = tid >> 1;
    const char* rowp = fin + (size_t)(b>>5)*1024 + (size_t)(b&31)*32;
    float acc = bfc[o];
    for (int cg = 0; cg < 64; ++cg) {
      f16x8 lo, hi;
      asm volatile("global_load_dwordx4 %0, %2, off sc0 sc1\n\t"
                   "global_load_dwordx4 %1, %2, off offset:16 sc0 sc1\n\t"
                   "s_waitcnt vmcnt(0)"
                   : "=&v"(lo), "=&v"(hi) : "v"(rowp + (size_t)cg*2048) : "memory");
      #pragma unroll
      for (int i = 0; i < 8; ++i) {
        acc += (float)lo[i] * Wfc[(size_t)(cg*16 + i)*Oo + o];
        acc += (float)hi[i] * Wfc[(size_t)(cg*16 + 8 + i)*Oo + o];
      }
    }
    out[(size_t)b*Oo + o] = acc;
  }
}

extern "C" void kernel_launch(void* const* d_in, const int* in_sizes, int n_in,
                              void* d_out, int out_size, void* d_ws, size_t ws_size,
                              hipStream_t stream) {
  const float* x   = (const float*)d_in[0];
  const float* Wf0 = (const float*)d_in[1];
  const float* bf0 = (const float*)d_in[2];
  const float* Wc0 = (const float*)d_in[3];
  const float* bc0 = (const float*)d_in[4];
  const float* Wf1 = (const float*)d_in[5];
  const float* bf1 = (const float*)d_in[6];
  const float* Wc1 = (const float*)d_in[7];
  const float* bc1 = (const float*)d_in[8];
  const float* Wfc = (const float*)d_in[9];
  const float* bfc = (const float*)d_in[10];

  init_fresh<<<64, 256, 0, stream>>>(d_ws);
  janet_persistent<<<NWG, 256, 0, stream>>>(x, Wf0, bf0, Wc0, bc0,
                                            Wf1, bf1, Wc1, bc1, Wfc, bfc,
                                            (float*)d_out, d_ws);
}